// Round 2
// baseline (208.543 us; speedup 1.0000x reference)
//
// Flash-attention SDPA (GQA 16:4), MI355X gfx950.
// fp32 q in, fp32 out; K pre-converted to bf16, V pre-converted AND
// pre-transposed to [kvg][d][key] bf16 in d_ws (prologue);
// XCD-local block mapping (g%8) keeps K/V L2-resident.
// S^T = K*Q^T keeps P in registers; max-free softmax; TM=128, 2 q-bands per
// wave, 256 thr, K dbuf + 1 barrier/tile, de-phased tile schedule (t0 rot).
// V BYPASSES LDS: the 59 us baseline was latency-bound (MFMA 34% + VALU 35%,
// ~70% issue idle) with the LDS pipe carrying both K and V reads plus V's
// perm-interleave staging, while VMEM sat idle (HBM 6.6%, K/V L2-resident).
// V^T in workspace lets PV B-fragments load directly from L2 (8B/lane,
// L1-reused by the block's 4 tile-synchronized waves): -32 ds_read,
// -16 ds_write, -8 perm per tile-wave, LDS 66.5->32.8 KB.
// This revision vs the NaN round: P-pack reverted from inline-asm
// v_cvt_pk_bf16_f32 to the PROVEN pack2_bf16 perm sequence (the asm was the
// only unproven primitive in the failing kernel; garbage P -> inf*0 in PV
// MFMA -> NaN matches the failure signature). No inline asm remains.
#include <hip/hip_runtime.h>
#include <hip/hip_bf16.h>

typedef unsigned short u16;
typedef short s16x4 __attribute__((ext_vector_type(4)));
typedef short s16x8 __attribute__((ext_vector_type(8)));
typedef float fx4 __attribute__((ext_vector_type(4)));
typedef unsigned ux2 __attribute__((ext_vector_type(2)));

#define BATCH 2
#define NHQ 16
#define NHKV 4
#define SEQ 2048
#define HD 64
#define TM 128
#define TN 128
#define NTILES (SEQ / TN)
#define NKV (BATCH * NHKV * SEQ * HD)   // 1,048,576 elems per tensor
// (1/sqrt(HD)) * log2(e)
#define QSCALE 0.18033688011112042f

// {lo16: bf16(a), hi16: bf16(b)}, round-half-up (+0x8000) then byte-perm.
__device__ __forceinline__ unsigned pack2_bf16(float a, float b) {
    const unsigned ua = __float_as_uint(a) + 0x8000u;
    const unsigned ub = __float_as_uint(b) + 0x8000u;
    return __builtin_amdgcn_perm(ub, ua, 0x07060302u);
}

// Prologue (merged, 1280 blocks x 256 thr):
//  blocks [0,1024):    K fp32 -> bf16 linear, 4 elems/thread.
//  blocks [1024,1280): V fp32 -> bf16 TRANSPOSED [kvg][d][key] via LDS tile.
//                      Each block: one kv-group, 64 keys x 64 d.
__global__ __launch_bounds__(256) void cvt_kv_kernel(
    const float* __restrict__ K, const float* __restrict__ V,
    u16* __restrict__ wsK, u16* __restrict__ wsV)
{
    __shared__ u16 tr[64][72];   // [d][key], stride 144B keeps 16B alignment
    const int tid = threadIdx.x;
    if (blockIdx.x < NKV / 1024) {
        const int i = (blockIdx.x * 256 + tid) * 4;
        const fx4 k4 = *(const fx4*)(K + i);
        ux2 ko;
        ko[0] = pack2_bf16(k4[0], k4[1]);
        ko[1] = pack2_bf16(k4[2], k4[3]);
        *(ux2*)(wsK + i) = ko;
    } else {
        const int b    = blockIdx.x - NKV / 1024;   // 0..255
        const int g    = b >> 5;                    // kv-group 0..7
        const int key0 = (b & 31) * 64;
        const float* src = V + ((size_t)g * SEQ + key0) * HD;
        // Read: thread t covers key rk, 16 d's starting rd -> 64B contiguous.
        const int rk = tid >> 2;          // key 0..63
        const int rd = (tid & 3) * 16;    // d0
#pragma unroll
        for (int j = 0; j < 4; j++) {
            const fx4 x = *(const fx4*)(src + rk * HD + rd + j * 4);
#pragma unroll
            for (int e = 0; e < 4; e++)
                tr[rd + j * 4 + e][rk] =
                    (u16)((__float_as_uint(x[e]) + 0x8000u) >> 16);
        }
        __syncthreads();
        // Write: thread t -> row d = t>>2, 16 keys; coalesced s16x8 pairs.
        const int wd = tid >> 2;          // d 0..63
        const int wk = (tid & 3) * 16;    // key chunk
        u16* dst = wsV + (size_t)(g * HD + wd) * SEQ + key0 + wk;
        *(s16x8*)(dst)     = *(const s16x8*)(&tr[wd][wk]);
        *(s16x8*)(dst + 8) = *(const s16x8*)(&tr[wd][wk + 8]);
    }
}

__global__ __launch_bounds__(256, 2) void ptSDPA_39668317946373_kernel(
    const float* __restrict__ gQ,
    const u16* __restrict__ wsK,
    const u16* __restrict__ wsV,
    float* __restrict__ gO)
{
    // K only in LDS now: 2 x 16 KB double buffer.
    __shared__ u16 shK[2][TN * HD];        // [buf][key][d], XOR-chunk swizzle

    const int tid = threadIdx.x;
    const int wv  = tid >> 6;       // 0..3, two 16-row q-bands per wave
    const int ln  = tid & 63;
    const int l15 = ln & 15;
    const int qd  = ln >> 4;        // quad 0..3

    // XCD-local decode: g%8 = kv-group (= batch*NHKV + hkv).
    const int g     = blockIdx.x;
    const int kvg   = g & 7;
    const int inner = g >> 3;        // 0..63
    const int qtb   = inner & 15;
    const int hqw   = inner >> 4;    // 0..3
    const int batch = kvg >> 2;
    const int hkv   = kvg & 3;
    const int head  = batch * NHQ + hkv * 4 + hqw;

    // De-phase: co-resident blocks start their tile loop at different
    // rotations so their compute phases decorrelate.
    const int t0 = (inner & 3) * 4;

    const float* q_base = gQ + (size_t)head * SEQ * HD;
    const u16*   k_base = wsK + (size_t)kvg * SEQ * HD;
    float*       o_base = gO + (size_t)head * SEQ * HD;
    // V^T base for this lane: row d = (ni*16 + l15), key offset qd*4.
    const u16*   vt_lane = wsV + ((size_t)(kvg * HD) + l15) * SEQ + qd * 4;

    const int qrow0 = qtb * TM;

    // Q fragments (B-operand of S^T MFMA: lane&15 = q, k = quad*8+j),
    // pre-scaled by QSCALE. Two bands mi = 0,1.
    s16x8 qfrag[2][2];
#pragma unroll
    for (int mi = 0; mi < 2; mi++) {
        const int row = qrow0 + wv * 32 + mi * 16 + l15;
#pragma unroll
        for (int ks = 0; ks < 2; ks++) {
            const int d0 = ks * 32 + qd * 8;
            const fx4 lo = *(const fx4*)(q_base + (size_t)row * HD + d0);
            const fx4 hi = *(const fx4*)(q_base + (size_t)row * HD + d0 + 4);
            union { unsigned u[4]; s16x8 v; } t;
            t.u[0] = pack2_bf16(lo[0] * QSCALE, lo[1] * QSCALE);
            t.u[1] = pack2_bf16(lo[2] * QSCALE, lo[3] * QSCALE);
            t.u[2] = pack2_bf16(hi[0] * QSCALE, hi[1] * QSCALE);
            t.u[3] = pack2_bf16(hi[2] * QSCALE, hi[3] * QSCALE);
            qfrag[mi][ks] = t.v;
        }
    }

    // O accumulators (C layout: col = d, row = q) + row-sum partials.
    fx4 oacc[2][4];
    float rsum[2] = {0.f, 0.f};
    const fx4 z4 = {0.f, 0.f, 0.f, 0.f};
#pragma unroll
    for (int mi = 0; mi < 2; mi++)
#pragma unroll
        for (int ni = 0; ni < 4; ni++) oacc[mi][ni] = z4;

    // K staging: thread covers one key row, half the head dim (32 d, bf16).
    const int skey  = tid & 127;
    const int shalf = tid >> 7;
    const u16* kp0 = k_base + skey * HD + shalf * 32;

    s16x8 kreg[4];   // 16 VGPRs of K prefetch state

    // First tile (t0): load then stage into buffer 0.
#pragma unroll
    for (int s = 0; s < 4; s++)
        kreg[s] = *(const s16x8*)(kp0 + (size_t)t0 * TN * HD + s * 8);
#pragma unroll
    for (int s = 0; s < 4; s++) {
        const int c = shalf * 4 + s;
        *(s16x8*)(shK[0] + skey * 64 + ((c ^ (skey & 7)) * 8)) = kreg[s];
    }

#pragma unroll 2
    for (int i = 0; i < NTILES; i++) {
        const int cur = i & 1;
        const int nxt = cur ^ 1;

        // Single barrier per tile: buf[cur] staged AND buf[nxt] readers done.
        __syncthreads();

        // Prefetch next K tile in this block's rotated order.
        if (i + 1 < NTILES) {
            const int tp = (t0 + i + 1) & (NTILES - 1);
            const u16* kp = kp0 + (size_t)tp * TN * HD;
#pragma unroll
            for (int s = 0; s < 4; s++) kreg[s] = *(const s16x8*)(kp + s * 8);
        }

        // S^T = K Q^T : C col = q (l15), row = key (quad*4+r).
        fx4 sc[2][8];
#pragma unroll
        for (int mi = 0; mi < 2; mi++)
#pragma unroll
            for (int kt = 0; kt < 8; kt++) sc[mi][kt] = z4;

        const int kb7 = l15 & 7;
#pragma unroll
        for (int ks = 0; ks < 2; ks++) {
            const int sw = ((ks * 4 + qd) ^ kb7) << 3;
#pragma unroll
            for (int kt = 0; kt < 8; kt++) {
                const s16x8 kf =
                    *(const s16x8*)(shK[cur] + kt * 1024 + l15 * 64 + sw);
#pragma unroll
                for (int mi = 0; mi < 2; mi++)
                    sc[mi][kt] = __builtin_amdgcn_mfma_f32_16x16x32_bf16(
                        kf, qfrag[mi][ks], sc[mi][kt], 0, 0, 0);
            }
        }

        // V fragments for the CURRENT tile, straight from L2 (V^T layout:
        // lane reads 4 contiguous keys at row d = ni*16+l15). Issued here so
        // the exp2/pack phase (~600 cyc) hides the ~200 cyc L2 latency.
        const int tc = (t0 + i) & (NTILES - 1);
        const u16* vt = vt_lane + (size_t)tc * TN;
        s16x4 vfr[8][4];
#pragma unroll
        for (int kt = 0; kt < 8; kt++)
#pragma unroll
            for (int ni = 0; ni < 4; ni++)
                vfr[kt][ni] =
                    *(const s16x4*)(vt + (size_t)ni * (16 * SEQ) + kt * 16);

        // exp2 in-register; pack into PV A-fragments (lane&15 = q,
        // k = quad*4+j == the S^T C layout).
        s16x4 pf[2][8];
#pragma unroll
        for (int mi = 0; mi < 2; mi++)
#pragma unroll
            for (int kt = 0; kt < 8; kt++) {
                const float p0 = __builtin_amdgcn_exp2f(sc[mi][kt][0]);
                const float p1 = __builtin_amdgcn_exp2f(sc[mi][kt][1]);
                const float p2 = __builtin_amdgcn_exp2f(sc[mi][kt][2]);
                const float p3 = __builtin_amdgcn_exp2f(sc[mi][kt][3]);
                rsum[mi] += (p0 + p1) + (p2 + p3);
                union { unsigned u[2]; s16x4 v; } pp;
                pp.u[0] = pack2_bf16(p0, p1);
                pp.u[1] = pack2_bf16(p2, p3);
                pf[mi][kt] = pp.v;
            }

        // O += P V as K=16 MFMAs; V-fragment = 4 contiguous keys from regs.
#pragma unroll
        for (int kt = 0; kt < 8; kt++) {
#pragma unroll
            for (int ni = 0; ni < 4; ni++) {
#pragma unroll
                for (int mi = 0; mi < 2; mi++)
                    oacc[mi][ni] = __builtin_amdgcn_mfma_f32_16x16x16bf16_1k(
                        pf[mi][kt], vfr[kt][ni], oacc[mi][ni], 0, 0, 0);
            }
        }

        // Stage prefetched K tile into the other buffer (no barrier: buf[nxt]
        // is not read until after the next loop-top barrier).
        if (i + 1 < NTILES) {
#pragma unroll
            for (int s = 0; s < 4; s++) {
                const int c = shalf * 4 + s;
                *(s16x8*)(shK[nxt] + skey * 64 + ((c ^ (skey & 7)) * 8)) = kreg[s];
            }
        }
    }

    // Epilogue: complete row sums (quads hold disjoint key slices of q=l15),
    // normalize, store fp32.
#pragma unroll
    for (int mi = 0; mi < 2; mi++) {
        float s = rsum[mi];
        s += __shfl_xor(s, 16, 64);
        s += __shfl_xor(s, 32, 64);   // lane L: full sum for q = (L&15)
        float inv[4];
#pragma unroll
        for (int r = 0; r < 4; r++)
            inv[r] = 1.0f / __shfl(s, qd * 4 + r, 64);
#pragma unroll
        for (int ni = 0; ni < 4; ni++)
#pragma unroll
            for (int r = 0; r < 4; r++) {
                const int qr = qrow0 + wv * 32 + mi * 16 + qd * 4 + r;
                o_base[(size_t)qr * HD + ni * 16 + l15] =
                    oacc[mi][ni][r] * inv[r];
            }
    }
}

extern "C" void kernel_launch(void* const* d_in, const int* in_sizes, int n_in,
                              void* d_out, int out_size, void* d_ws, size_t ws_size,
                              hipStream_t stream) {
    const float* q = (const float*)d_in[0];
    const float* k = (const float*)d_in[1];
    const float* v = (const float*)d_in[2];
    float*       o = (float*)d_out;
    u16* wsK = (u16*)d_ws;            // 2 MB
    u16* wsV = wsK + NKV;             // 2 MB, transposed [kvg][d][key]
    const int kblocks = NKV / 1024;                      // 1024
    const int vblocks = (BATCH * NHKV) * (SEQ / 64);     // 256
    cvt_kv_kernel<<<kblocks + vblocks, 256, 0, stream>>>(k, v, wsK, wsV);
    const dim3 grid(BATCH * NHQ * (SEQ / TM));   // 512 workgroups, 256 thr
    ptSDPA_39668317946373_kernel<<<grid, 256, 0, stream>>>(q, wsK, wsV, o);
}

// Round 4
// 126.267 us; speedup vs baseline: 1.6516x; 1.6516x over previous
//
// Flash-attention SDPA (GQA 16:4), MI355X gfx950.
// fp32 q in, fp32 out; K/V pre-converted to bf16 in d_ws (prologue);
// XCD-local block mapping (g%8) keeps K/V L2-resident.
// S^T = K*Q^T keeps P in registers; max-free softmax; TM=128, 2 q-bands per
// wave, 256 thr, dbuf + 1 barrier/tile, de-phased tile order (t0 rot).
// V stays in LDS (R1/R2 lesson: V-from-L2 gather = 16 segments/instr ->
// 145 us; LDS handles the scatter for free, 0 conflicts).
// R3 = R2 resubmitted verbatim: the R2 bench died on container infra
// ("MI355X container failed twice"), no kernel evidence.
// This revision vs the 59 us baseline:
//  (a) PER-KT SOFTWARE PIPELINE: tile body fused into one kt loop with
//      skew-1 (issue QK(kt+1) MFMAs, then V ds_reads(kt), exp2/pack(kt),
//      PV(kt)). Baseline ran phase-separated QK->exp2->PV passes, so each
//      wave occupied one pipe at a time (MFMA 34% + VALU 35%, both
//      half-idle). Fusion alternates ~14 MFMA / ~26 VALU per kt so one
//      wave feeds both pipes; QK latency hides under prior kt's exp2.
//  (b) ROW-SUM VIA ONES-MFMA: racc[mi] = mfma(pf[mi], ones, racc[mi])
//      replaces 48 serial VALU adds/tile-wave + the epilogue shuffle
//      reduce (MFMA row = full per-q sum). Denominator now sums the
//      bf16-rounded P, consistent with the numerator.
#include <hip/hip_runtime.h>
#include <hip/hip_bf16.h>

typedef unsigned short u16;
typedef short s16x4 __attribute__((ext_vector_type(4)));
typedef short s16x8 __attribute__((ext_vector_type(8)));
typedef float fx4 __attribute__((ext_vector_type(4)));
typedef unsigned ux2 __attribute__((ext_vector_type(2)));

#define BATCH 2
#define NHQ 16
#define NHKV 4
#define SEQ 2048
#define HD 64
#define TM 128
#define TN 128
#define NTILES (SEQ / TN)
#define VSTRIDE 132   // u16 row stride of shVt (66 dwords == 2 mod 32)
#define NKV (BATCH * NHKV * SEQ * HD)   // 1,048,576 elems per tensor
// (1/sqrt(HD)) * log2(e)
#define QSCALE 0.18033688011112042f

// {lo16: bf16(a), hi16: bf16(b)}, round-half-up (+0x8000) then byte-perm.
__device__ __forceinline__ unsigned pack2_bf16(float a, float b) {
    const unsigned ua = __float_as_uint(a) + 0x8000u;
    const unsigned ub = __float_as_uint(b) + 0x8000u;
    return __builtin_amdgcn_perm(ub, ua, 0x07060302u);
}
// interleave low/high u16 halves of two dwords (row0, row1 of V)
__device__ __forceinline__ unsigned ilv_lo(unsigned r0, unsigned r1) {
    return __builtin_amdgcn_perm(r1, r0, 0x05040100u);
}
__device__ __forceinline__ unsigned ilv_hi(unsigned r0, unsigned r1) {
    return __builtin_amdgcn_perm(r1, r0, 0x07060302u);
}

// Prologue: K,V fp32 -> bf16 into workspace. 1024 blocks x 256 thr x 4 elems.
__global__ __launch_bounds__(256) void cvt_kv_kernel(
    const float* __restrict__ K, const float* __restrict__ V,
    u16* __restrict__ wsK, u16* __restrict__ wsV)
{
    const int i = (blockIdx.x * 256 + threadIdx.x) * 4;
    const fx4 k4 = *(const fx4*)(K + i);
    const fx4 v4 = *(const fx4*)(V + i);
    ux2 ko, vo;
    ko[0] = pack2_bf16(k4[0], k4[1]);
    ko[1] = pack2_bf16(k4[2], k4[3]);
    vo[0] = pack2_bf16(v4[0], v4[1]);
    vo[1] = pack2_bf16(v4[2], v4[3]);
    *(ux2*)(wsK + i) = ko;
    *(ux2*)(wsV + i) = vo;
}

__global__ __launch_bounds__(256, 2) void ptSDPA_39668317946373_kernel(
    const float* __restrict__ gQ,
    const u16* __restrict__ wsK,
    const u16* __restrict__ wsV,
    float* __restrict__ gO)
{
    // Double-buffered tiles: 2 x (16 + 16.5) KB = 65.8 KB -> 2 blocks/CU.
    __shared__ u16 shK[2][TN * HD];        // [buf][key][d], XOR-chunk swizzle
    __shared__ u16 shVt[2][HD * VSTRIDE];  // [buf][d][key], padded stride

    const int tid = threadIdx.x;
    const int wv  = tid >> 6;       // 0..3, two 16-row q-bands per wave
    const int ln  = tid & 63;
    const int l15 = ln & 15;
    const int qd  = ln >> 4;        // quad 0..3

    // XCD-local decode: g%8 = kv-group (= batch*NHKV + hkv).
    const int g     = blockIdx.x;
    const int kvg   = g & 7;
    const int inner = g >> 3;        // 0..63
    const int qtb   = inner & 15;
    const int hqw   = inner >> 4;    // 0..3
    const int batch = kvg >> 2;
    const int hkv   = kvg & 3;
    const int head  = batch * NHQ + hkv * 4 + hqw;

    // De-phase: co-resident blocks start their tile loop at different
    // rotations so their compute phases decorrelate.
    const int t0 = (inner & 3) * 4;

    const float* q_base = gQ + (size_t)head * SEQ * HD;
    const u16*   k_base = wsK + (size_t)kvg * SEQ * HD;
    const u16*   v_base = wsV + (size_t)kvg * SEQ * HD;
    float*       o_base = gO + (size_t)head * SEQ * HD;

    const int qrow0 = qtb * TM;

    // Q fragments (B-operand of S^T MFMA: lane&15 = q, k = quad*8+j),
    // pre-scaled by QSCALE. Two bands mi = 0,1.
    s16x8 qfrag[2][2];
#pragma unroll
    for (int mi = 0; mi < 2; mi++) {
        const int row = qrow0 + wv * 32 + mi * 16 + l15;
#pragma unroll
        for (int ks = 0; ks < 2; ks++) {
            const int d0 = ks * 32 + qd * 8;
            const fx4 lo = *(const fx4*)(q_base + (size_t)row * HD + d0);
            const fx4 hi = *(const fx4*)(q_base + (size_t)row * HD + d0 + 4);
            union { unsigned u[4]; s16x8 v; } t;
            t.u[0] = pack2_bf16(lo[0] * QSCALE, lo[1] * QSCALE);
            t.u[1] = pack2_bf16(lo[2] * QSCALE, lo[3] * QSCALE);
            t.u[2] = pack2_bf16(hi[0] * QSCALE, hi[1] * QSCALE);
            t.u[3] = pack2_bf16(hi[2] * QSCALE, hi[3] * QSCALE);
            qfrag[mi][ks] = t.v;
        }
    }

    // O accumulators (C layout: col = d, row = q) + row-sum accumulators.
    fx4 oacc[2][4];
    fx4 racc[2];
    const fx4 z4 = {0.f, 0.f, 0.f, 0.f};
#pragma unroll
    for (int mi = 0; mi < 2; mi++) {
        racc[mi] = z4;
#pragma unroll
        for (int ni = 0; ni < 4; ni++) oacc[mi][ni] = z4;
    }
    // B-operand of the row-sum MFMA: all-ones bf16.
    const s16x4 ones4 = {(short)0x3F80, (short)0x3F80,
                         (short)0x3F80, (short)0x3F80};

    // K staging: thread covers one key row, half the head dim (32 d, bf16).
    const int skey  = tid & 127;
    const int shalf = tid >> 7;
    const u16* kp0 = k_base + skey * HD + shalf * 32;
    // V staging: thread covers a key PAIR (2*ln) over 16 d (wave's band).
    const int vkey = ln * 2;
    const int vd0  = wv * 16;
    const u16* vp0 = v_base + vkey * HD + vd0;

    s16x8 kreg[4], vreg[4];   // 32 VGPRs of prefetch state

    // First tile (t0): load then stage into buffer 0.
#pragma unroll
    for (int s = 0; s < 4; s++)
        kreg[s] = *(const s16x8*)(kp0 + (size_t)t0 * TN * HD + s * 8);
    {
        const u16* vp = vp0 + (size_t)t0 * TN * HD;
        vreg[0] = *(const s16x8*)(vp);
        vreg[1] = *(const s16x8*)(vp + 8);
        vreg[2] = *(const s16x8*)(vp + HD);
        vreg[3] = *(const s16x8*)(vp + HD + 8);
    }
#pragma unroll
    for (int s = 0; s < 4; s++) {
        const int c = shalf * 4 + s;
        *(s16x8*)(shK[0] + skey * 64 + ((c ^ (skey & 7)) * 8)) = kreg[s];
    }
#pragma unroll
    for (int h = 0; h < 2; h++) {
        union { s16x8 v; unsigned u[4]; } r0, r1;
        r0.v = vreg[h];
        r1.v = vreg[2 + h];
#pragma unroll
        for (int c2 = 0; c2 < 4; c2++) {
            const int d = vd0 + h * 8 + c2 * 2;
            *(unsigned*)(shVt[0] + d * VSTRIDE + vkey) = ilv_lo(r0.u[c2], r1.u[c2]);
            *(unsigned*)(shVt[0] + (d + 1) * VSTRIDE + vkey) = ilv_hi(r0.u[c2], r1.u[c2]);
        }
    }

#pragma unroll 2
    for (int i = 0; i < NTILES; i++) {
        const int cur = i & 1;
        const int nxt = cur ^ 1;

        // Single barrier per tile: buf[cur] staged AND buf[nxt] readers done.
        __syncthreads();

        // Prefetch the next tile in this block's rotated order.
        if (i + 1 < NTILES) {
            const int tp = (t0 + i + 1) & (NTILES - 1);
            const u16* kp = kp0 + (size_t)tp * TN * HD;
            const u16* vp = vp0 + (size_t)tp * TN * HD;
#pragma unroll
            for (int s = 0; s < 4; s++) kreg[s] = *(const s16x8*)(kp + s * 8);
            vreg[0] = *(const s16x8*)(vp);
            vreg[1] = *(const s16x8*)(vp + 8);
            vreg[2] = *(const s16x8*)(vp + HD);
            vreg[3] = *(const s16x8*)(vp + HD + 8);
        }

        // Fused per-kt pipeline, skew-1: QK(kt+1) in flight while
        // exp2/pack(kt) runs on the VALU, then PV(kt) on the matrix pipe.
        // scp ping-pongs on kt parity; all indices static after unroll.
        const int kb7 = l15 & 7;
        const int sw0 = (qd ^ kb7) << 3;          // ks=0 chunk swizzle
        const int sw1 = ((4 + qd) ^ kb7) << 3;    // ks=1 chunk swizzle
        const u16* kRow = shK[cur] + l15 * 64;

        fx4 scp[2][2];   // [kt&1][mi]
        {   // QK(0)
            const s16x8 kf0 = *(const s16x8*)(kRow + sw0);
            const s16x8 kf1 = *(const s16x8*)(kRow + sw1);
#pragma unroll
            for (int mi = 0; mi < 2; mi++)
                scp[0][mi] = __builtin_amdgcn_mfma_f32_16x16x32_bf16(
                    kf0, qfrag[mi][0], z4, 0, 0, 0);
#pragma unroll
            for (int mi = 0; mi < 2; mi++)
                scp[0][mi] = __builtin_amdgcn_mfma_f32_16x16x32_bf16(
                    kf1, qfrag[mi][1], scp[0][mi], 0, 0, 0);
        }

#pragma unroll
        for (int kt = 0; kt < 8; kt++) {
            const int p = kt & 1;
            if (kt < 7) {   // QK(kt+1)
                const s16x8 kf0 = *(const s16x8*)(kRow + (kt + 1) * 1024 + sw0);
                const s16x8 kf1 = *(const s16x8*)(kRow + (kt + 1) * 1024 + sw1);
#pragma unroll
                for (int mi = 0; mi < 2; mi++)
                    scp[p ^ 1][mi] = __builtin_amdgcn_mfma_f32_16x16x32_bf16(
                        kf0, qfrag[mi][0], z4, 0, 0, 0);
#pragma unroll
                for (int mi = 0; mi < 2; mi++)
                    scp[p ^ 1][mi] = __builtin_amdgcn_mfma_f32_16x16x32_bf16(
                        kf1, qfrag[mi][1], scp[p ^ 1][mi], 0, 0, 0);
            }

            // V fragments for kt (in flight during exp2/pack below).
            // dword = 66*d + key/2: conflict-free (measured 0).
            const int kb = kt * 16 + qd * 4;
            s16x4 vf[4];
#pragma unroll
            for (int ni = 0; ni < 4; ni++)
                vf[ni] = *(const s16x4*)(
                    shVt[cur] + (ni * 16 + l15) * VSTRIDE + kb);

            // exp2 in-register; pack into PV A-fragments (lane&15 = q,
            // k = quad*4+j == the S^T C layout).
            s16x4 pf[2];
#pragma unroll
            for (int mi = 0; mi < 2; mi++) {
                const float p0 = __builtin_amdgcn_exp2f(scp[p][mi][0]);
                const float p1 = __builtin_amdgcn_exp2f(scp[p][mi][1]);
                const float p2 = __builtin_amdgcn_exp2f(scp[p][mi][2]);
                const float p3 = __builtin_amdgcn_exp2f(scp[p][mi][3]);
                union { unsigned u[2]; s16x4 v; } pp;
                pp.u[0] = pack2_bf16(p0, p1);
                pp.u[1] = pack2_bf16(p2, p3);
                pf[mi] = pp.v;
            }

            // Row sums on the matrix pipe: racc[mi][r] accumulates the
            // full key-sum for q = qd*4+r (uniform across l15).
#pragma unroll
            for (int mi = 0; mi < 2; mi++)
                racc[mi] = __builtin_amdgcn_mfma_f32_16x16x16bf16_1k(
                    pf[mi], ones4, racc[mi], 0, 0, 0);

            // O += P V as K=16 MFMAs.
#pragma unroll
            for (int ni = 0; ni < 4; ni++) {
#pragma unroll
                for (int mi = 0; mi < 2; mi++)
                    oacc[mi][ni] = __builtin_amdgcn_mfma_f32_16x16x16bf16_1k(
                        pf[mi], vf[ni], oacc[mi][ni], 0, 0, 0);
            }
        }

        // Stage prefetched tile into the other buffer (no barrier: buf[nxt]
        // is not read until after the next loop-top barrier).
        if (i + 1 < NTILES) {
#pragma unroll
            for (int s = 0; s < 4; s++) {
                const int c = shalf * 4 + s;
                *(s16x8*)(shK[nxt] + skey * 64 + ((c ^ (skey & 7)) * 8)) = kreg[s];
            }
#pragma unroll
            for (int h = 0; h < 2; h++) {
                union { s16x8 v; unsigned u[4]; } r0, r1;
                r0.v = vreg[h];
                r1.v = vreg[2 + h];
#pragma unroll
                for (int c2 = 0; c2 < 4; c2++) {
                    const int d = vd0 + h * 8 + c2 * 2;
                    *(unsigned*)(shVt[nxt] + d * VSTRIDE + vkey) =
                        ilv_lo(r0.u[c2], r1.u[c2]);
                    *(unsigned*)(shVt[nxt] + (d + 1) * VSTRIDE + vkey) =
                        ilv_hi(r0.u[c2], r1.u[c2]);
                }
            }
        }
    }

    // Epilogue: racc already holds full row sums (q = qd*4+r); normalize,
    // store fp32. No cross-lane reduction needed.
#pragma unroll
    for (int mi = 0; mi < 2; mi++) {
        float inv[4];
#pragma unroll
        for (int r = 0; r < 4; r++) inv[r] = 1.0f / racc[mi][r];
#pragma unroll
        for (int ni = 0; ni < 4; ni++)
#pragma unroll
            for (int r = 0; r < 4; r++) {
                const int qr = qrow0 + wv * 32 + mi * 16 + qd * 4 + r;
                o_base[(size_t)qr * HD + ni * 16 + l15] =
                    oacc[mi][ni][r] * inv[r];
            }
    }
}

extern "C" void kernel_launch(void* const* d_in, const int* in_sizes, int n_in,
                              void* d_out, int out_size, void* d_ws, size_t ws_size,
                              hipStream_t stream) {
    const float* q = (const float*)d_in[0];
    const float* k = (const float*)d_in[1];
    const float* v = (const float*)d_in[2];
    float*       o = (float*)d_out;
    u16* wsK = (u16*)d_ws;            // 2 MB
    u16* wsV = wsK + NKV;             // 2 MB  (4 MB total workspace)
    cvt_kv_kernel<<<NKV / 1024, 256, 0, stream>>>(k, v, wsK, wsV);
    const dim3 grid(BATCH * NHQ * (SEQ / TM));   // 512 workgroups, 256 thr
    ptSDPA_39668317946373_kernel<<<grid, 256, 0, stream>>>(q, wsK, wsV, o);
}

// Round 5
// 123.262 us; speedup vs baseline: 1.6919x; 1.0244x over previous
//
// Flash-attention SDPA (GQA 16:4), MI355X gfx950.
// fp32 q in, fp32 out; K/V pre-converted to bf16 in d_ws (prologue);
// XCD-local block mapping (g%8) keeps K/V L2-resident.
// S^T = K*Q^T keeps P in registers; max-free softmax; ones-MFMA row-sum
// (denominator sums bf16-rounded P, consistent with numerator).
// V stays in LDS (R1/R2 lesson: V-from-L2 gather = 16 segments/instr ->
// 145 us; LDS handles the scatter for free, 0 conflicts).
// This revision: 8-WAVE BLOCKS (512 thr), ONE 16-row q-band per wave.
// R4 post-mortem: fused ILP pipeline was neutral (59->61.5 us) -> the
// stall is TLP starvation, not phase separation: issue occupancy ~18%
// (820 issue-cyc per wave-tile vs 9.2K cyc wall, only 2 waves/SIMD;
// grid 512x256thr = 8 waves/CU, LDS 66.5KB = 2 blocks/CU).
// 512-thr blocks keep grid=512 and LDS unchanged but give 16 waves/CU
// = 4 waves/SIMD. Staging specializes: waves 0-3 stage V (old 256-thr
// pattern verbatim), waves 4-7 stage K. LDS read traffic doubles
// (~9 MB/CU-pass ~ 30-44 us floor) - below predicted wall, won't bind.
#include <hip/hip_runtime.h>
#include <hip/hip_bf16.h>

typedef unsigned short u16;
typedef short s16x4 __attribute__((ext_vector_type(4)));
typedef short s16x8 __attribute__((ext_vector_type(8)));
typedef float fx4 __attribute__((ext_vector_type(4)));
typedef unsigned ux2 __attribute__((ext_vector_type(2)));

#define BATCH 2
#define NHQ 16
#define NHKV 4
#define SEQ 2048
#define HD 64
#define TM 128
#define TN 128
#define NTILES (SEQ / TN)
#define VSTRIDE 132   // u16 row stride of shVt (66 dwords == 2 mod 32)
#define NKV (BATCH * NHKV * SEQ * HD)   // 1,048,576 elems per tensor
// (1/sqrt(HD)) * log2(e)
#define QSCALE 0.18033688011112042f

// {lo16: bf16(a), hi16: bf16(b)}, round-half-up (+0x8000) then byte-perm.
__device__ __forceinline__ unsigned pack2_bf16(float a, float b) {
    const unsigned ua = __float_as_uint(a) + 0x8000u;
    const unsigned ub = __float_as_uint(b) + 0x8000u;
    return __builtin_amdgcn_perm(ub, ua, 0x07060302u);
}
// interleave low/high u16 halves of two dwords (row0, row1 of V)
__device__ __forceinline__ unsigned ilv_lo(unsigned r0, unsigned r1) {
    return __builtin_amdgcn_perm(r1, r0, 0x05040100u);
}
__device__ __forceinline__ unsigned ilv_hi(unsigned r0, unsigned r1) {
    return __builtin_amdgcn_perm(r1, r0, 0x07060302u);
}

// Prologue: K,V fp32 -> bf16 into workspace. 1024 blocks x 256 thr x 4 elems.
__global__ __launch_bounds__(256) void cvt_kv_kernel(
    const float* __restrict__ K, const float* __restrict__ V,
    u16* __restrict__ wsK, u16* __restrict__ wsV)
{
    const int i = (blockIdx.x * 256 + threadIdx.x) * 4;
    const fx4 k4 = *(const fx4*)(K + i);
    const fx4 v4 = *(const fx4*)(V + i);
    ux2 ko, vo;
    ko[0] = pack2_bf16(k4[0], k4[1]);
    ko[1] = pack2_bf16(k4[2], k4[3]);
    vo[0] = pack2_bf16(v4[0], v4[1]);
    vo[1] = pack2_bf16(v4[2], v4[3]);
    *(ux2*)(wsK + i) = ko;
    *(ux2*)(wsV + i) = vo;
}

__global__ __launch_bounds__(512, 4) void ptSDPA_39668317946373_kernel(
    const float* __restrict__ gQ,
    const u16* __restrict__ wsK,
    const u16* __restrict__ wsV,
    float* __restrict__ gO)
{
    // Double-buffered tiles: 2 x (16 + 16.5) KB = 65 KB -> 2 blocks/CU.
    __shared__ u16 shK[2][TN * HD];        // [buf][key][d], XOR-chunk swizzle
    __shared__ u16 shVt[2][HD * VSTRIDE];  // [buf][d][key], padded stride

    const int tid = threadIdx.x;
    const int wv  = tid >> 6;       // 0..7, ONE 16-row q-band per wave
    const int ln  = tid & 63;
    const int l15 = ln & 15;
    const int qd  = ln >> 4;        // quad 0..3

    // XCD-local decode: g%8 = kv-group (= batch*NHKV + hkv).
    const int g     = blockIdx.x;
    const int kvg   = g & 7;
    const int inner = g >> 3;        // 0..63
    const int qtb   = inner & 15;
    const int hqw   = inner >> 4;    // 0..3
    const int batch = kvg >> 2;
    const int hkv   = kvg & 3;
    const int head  = batch * NHQ + hkv * 4 + hqw;

    // De-phase: co-resident blocks start their tile loop at different
    // rotations so their compute phases decorrelate.
    const int t0 = (inner & 3) * 4;

    const float* q_base = gQ + (size_t)head * SEQ * HD;
    const u16*   k_base = wsK + (size_t)kvg * SEQ * HD;
    const u16*   v_base = wsV + (size_t)kvg * SEQ * HD;
    float*       o_base = gO + (size_t)head * SEQ * HD;

    const int qrow0 = qtb * TM;

    // Q fragments (B-operand of S^T MFMA: lane&15 = q, k = quad*8+j),
    // pre-scaled by QSCALE. One band per wave.
    s16x8 qfrag[2];
    {
        const int row = qrow0 + wv * 16 + l15;
#pragma unroll
        for (int ks = 0; ks < 2; ks++) {
            const int d0 = ks * 32 + qd * 8;
            const fx4 lo = *(const fx4*)(q_base + (size_t)row * HD + d0);
            const fx4 hi = *(const fx4*)(q_base + (size_t)row * HD + d0 + 4);
            union { unsigned u[4]; s16x8 v; } t;
            t.u[0] = pack2_bf16(lo[0] * QSCALE, lo[1] * QSCALE);
            t.u[1] = pack2_bf16(lo[2] * QSCALE, lo[3] * QSCALE);
            t.u[2] = pack2_bf16(hi[0] * QSCALE, hi[1] * QSCALE);
            t.u[3] = pack2_bf16(hi[2] * QSCALE, hi[3] * QSCALE);
            qfrag[ks] = t.v;
        }
    }

    // O accumulators (C layout: col = d, row = q) + row-sum accumulator.
    fx4 oacc[4];
    fx4 racc;
    const fx4 z4 = {0.f, 0.f, 0.f, 0.f};
    racc = z4;
#pragma unroll
    for (int ni = 0; ni < 4; ni++) oacc[ni] = z4;
    // B-operand of the row-sum MFMA: all-ones bf16.
    const s16x4 ones4 = {(short)0x3F80, (short)0x3F80,
                         (short)0x3F80, (short)0x3F80};

    // Staging split by wave group (wave-uniform branch):
    //  waves 0-3 (tid 0..255):   V stager — key pair 2*ln over 16 d band.
    //  waves 4-7 (tid 256..511): K stager — one key row, half the head dim.
    const bool isV = (wv < 4);
    const int  st  = isV ? tid : (tid - 256);
    // V-stager params
    const int vkey = (st & 63) * 2;
    const int vd0  = (st >> 6) * 16;
    const u16* vp0 = v_base + vkey * HD + vd0;
    // K-stager params
    const int skey  = st & 127;
    const int shalf = st >> 7;
    const u16* kp0 = k_base + skey * HD + shalf * 32;

    s16x8 preg[4];   // 16 VGPRs of prefetch state (K or V role)

    // First tile (t0): load then stage into buffer 0.
    if (isV) {
        const u16* vp = vp0 + (size_t)t0 * TN * HD;
        preg[0] = *(const s16x8*)(vp);
        preg[1] = *(const s16x8*)(vp + 8);
        preg[2] = *(const s16x8*)(vp + HD);
        preg[3] = *(const s16x8*)(vp + HD + 8);
#pragma unroll
        for (int h = 0; h < 2; h++) {
            union { s16x8 v; unsigned u[4]; } r0, r1;
            r0.v = preg[h];
            r1.v = preg[2 + h];
#pragma unroll
            for (int c2 = 0; c2 < 4; c2++) {
                const int d = vd0 + h * 8 + c2 * 2;
                *(unsigned*)(shVt[0] + d * VSTRIDE + vkey) =
                    ilv_lo(r0.u[c2], r1.u[c2]);
                *(unsigned*)(shVt[0] + (d + 1) * VSTRIDE + vkey) =
                    ilv_hi(r0.u[c2], r1.u[c2]);
            }
        }
    } else {
#pragma unroll
        for (int s = 0; s < 4; s++)
            preg[s] = *(const s16x8*)(kp0 + (size_t)t0 * TN * HD + s * 8);
#pragma unroll
        for (int s = 0; s < 4; s++) {
            const int c = shalf * 4 + s;
            *(s16x8*)(shK[0] + skey * 64 + ((c ^ (skey & 7)) * 8)) = preg[s];
        }
    }

#pragma unroll 2
    for (int i = 0; i < NTILES; i++) {
        const int cur = i & 1;
        const int nxt = cur ^ 1;

        // Single barrier per tile: buf[cur] staged AND buf[nxt] readers done.
        __syncthreads();

        // Prefetch the next tile in this block's rotated order.
        if (i + 1 < NTILES) {
            const int tp = (t0 + i + 1) & (NTILES - 1);
            if (isV) {
                const u16* vp = vp0 + (size_t)tp * TN * HD;
                preg[0] = *(const s16x8*)(vp);
                preg[1] = *(const s16x8*)(vp + 8);
                preg[2] = *(const s16x8*)(vp + HD);
                preg[3] = *(const s16x8*)(vp + HD + 8);
            } else {
                const u16* kp = kp0 + (size_t)tp * TN * HD;
#pragma unroll
                for (int s = 0; s < 4; s++)
                    preg[s] = *(const s16x8*)(kp + s * 8);
            }
        }

        // Fused per-kt pipeline, skew-1: QK(kt+1) in flight while
        // exp2/pack(kt) runs on the VALU, then PV(kt) on the matrix pipe.
        const int kb7 = l15 & 7;
        const int sw0 = (qd ^ kb7) << 3;          // ks=0 chunk swizzle
        const int sw1 = ((4 + qd) ^ kb7) << 3;    // ks=1 chunk swizzle
        const u16* kRow = shK[cur] + l15 * 64;

        fx4 scp[2];   // [kt&1]
        {   // QK(0)
            const s16x8 kf0 = *(const s16x8*)(kRow + sw0);
            const s16x8 kf1 = *(const s16x8*)(kRow + sw1);
            scp[0] = __builtin_amdgcn_mfma_f32_16x16x32_bf16(
                kf0, qfrag[0], z4, 0, 0, 0);
            scp[0] = __builtin_amdgcn_mfma_f32_16x16x32_bf16(
                kf1, qfrag[1], scp[0], 0, 0, 0);
        }

#pragma unroll
        for (int kt = 0; kt < 8; kt++) {
            const int p = kt & 1;
            if (kt < 7) {   // QK(kt+1)
                const s16x8 kf0 = *(const s16x8*)(kRow + (kt + 1) * 1024 + sw0);
                const s16x8 kf1 = *(const s16x8*)(kRow + (kt + 1) * 1024 + sw1);
                scp[p ^ 1] = __builtin_amdgcn_mfma_f32_16x16x32_bf16(
                    kf0, qfrag[0], z4, 0, 0, 0);
                scp[p ^ 1] = __builtin_amdgcn_mfma_f32_16x16x32_bf16(
                    kf1, qfrag[1], scp[p ^ 1], 0, 0, 0);
            }

            // V fragments for kt (in flight during exp2/pack below).
            // dword = 66*d + key/2: conflict-free (measured 0).
            const int kb = kt * 16 + qd * 4;
            s16x4 vf[4];
#pragma unroll
            for (int ni = 0; ni < 4; ni++)
                vf[ni] = *(const s16x4*)(
                    shVt[cur] + (ni * 16 + l15) * VSTRIDE + kb);

            // exp2 in-register; pack into PV A-fragment (lane&15 = q,
            // k = quad*4+j == the S^T C layout).
            const float p0 = __builtin_amdgcn_exp2f(scp[p][0]);
            const float p1 = __builtin_amdgcn_exp2f(scp[p][1]);
            const float p2 = __builtin_amdgcn_exp2f(scp[p][2]);
            const float p3 = __builtin_amdgcn_exp2f(scp[p][3]);
            union { unsigned u[2]; s16x4 v; } pp;
            pp.u[0] = pack2_bf16(p0, p1);
            pp.u[1] = pack2_bf16(p2, p3);
            const s16x4 pf = pp.v;

            // Row sum on the matrix pipe: racc[r] accumulates the full
            // key-sum for q = qd*4+r (uniform across l15).
            racc = __builtin_amdgcn_mfma_f32_16x16x16bf16_1k(
                pf, ones4, racc, 0, 0, 0);

            // O += P V as K=16 MFMAs.
#pragma unroll
            for (int ni = 0; ni < 4; ni++)
                oacc[ni] = __builtin_amdgcn_mfma_f32_16x16x16bf16_1k(
                    pf, vf[ni], oacc[ni], 0, 0, 0);
        }

        // Stage prefetched tile into the other buffer (no barrier: buf[nxt]
        // is not read until after the next loop-top barrier).
        if (i + 1 < NTILES) {
            if (isV) {
#pragma unroll
                for (int h = 0; h < 2; h++) {
                    union { s16x8 v; unsigned u[4]; } r0, r1;
                    r0.v = preg[h];
                    r1.v = preg[2 + h];
#pragma unroll
                    for (int c2 = 0; c2 < 4; c2++) {
                        const int d = vd0 + h * 8 + c2 * 2;
                        *(unsigned*)(shVt[nxt] + d * VSTRIDE + vkey) =
                            ilv_lo(r0.u[c2], r1.u[c2]);
                        *(unsigned*)(shVt[nxt] + (d + 1) * VSTRIDE + vkey) =
                            ilv_hi(r0.u[c2], r1.u[c2]);
                    }
                }
            } else {
#pragma unroll
                for (int s = 0; s < 4; s++) {
                    const int c = shalf * 4 + s;
                    *(s16x8*)(shK[nxt] + skey * 64 + ((c ^ (skey & 7)) * 8)) =
                        preg[s];
                }
            }
        }
    }

    // Epilogue: racc already holds full row sums (q = qd*4+r); normalize,
    // store fp32. No cross-lane reduction needed.
    {
        float inv[4];
#pragma unroll
        for (int r = 0; r < 4; r++) inv[r] = 1.0f / racc[r];
#pragma unroll
        for (int ni = 0; ni < 4; ni++)
#pragma unroll
            for (int r = 0; r < 4; r++) {
                const int qr = qrow0 + wv * 16 + qd * 4 + r;
                o_base[(size_t)qr * HD + ni * 16 + l15] =
                    oacc[ni][r] * inv[r];
            }
    }
}

extern "C" void kernel_launch(void* const* d_in, const int* in_sizes, int n_in,
                              void* d_out, int out_size, void* d_ws, size_t ws_size,
                              hipStream_t stream) {
    const float* q = (const float*)d_in[0];
    const float* k = (const float*)d_in[1];
    const float* v = (const float*)d_in[2];
    float*       o = (float*)d_out;
    u16* wsK = (u16*)d_ws;            // 2 MB
    u16* wsV = wsK + NKV;             // 2 MB  (4 MB total workspace)
    cvt_kv_kernel<<<NKV / 1024, 256, 0, stream>>>(k, v, wsK, wsV);
    const dim3 grid(BATCH * NHQ * (SEQ / TM));   // 512 workgroups, 512 thr
    ptSDPA_39668317946373_kernel<<<grid, 512, 0, stream>>>(q, wsK, wsV, o);
}